// Round 13
// baseline (28500.314 us; speedup 1.0000x reference)
//
#include <hip/hip_runtime.h>

// Problem constants (from setup_inputs: B=16, N=16384, D=128, S=N/4)
#define BATCH    16
#define NPTS     16384
#define NSAMP    4096
#define NTHREADS 1024
#define SUBT     512     // threads per sub-batch (waves 0-7 = batch A, 8-15 = B)
#define PPT      32      // points per thread = 2 cells of 16
#define NWSUB    8

// DPP move helper (disabled lanes keep old value = own value)
template<int CTRL, int RM>
__device__ __forceinline__ float dpp_movf(float v) {
    return __int_as_float(__builtin_amdgcn_update_dpp(
        __float_as_int(v), __float_as_int(v), CTRL, RM, 0xF, false));
}
__device__ __forceinline__ float wave_max64(float v) {
    v = fmaxf(v, dpp_movf<0x111, 0xF>(v));   // row_shr:1
    v = fmaxf(v, dpp_movf<0x112, 0xF>(v));   // row_shr:2
    v = fmaxf(v, dpp_movf<0x114, 0xF>(v));   // row_shr:4
    v = fmaxf(v, dpp_movf<0x118, 0xF>(v));   // row_shr:8
    v = fmaxf(v, dpp_movf<0x142, 0xA>(v));   // row_bcast:15
    v = fmaxf(v, dpp_movf<0x143, 0xC>(v));   // row_bcast:31 -> lane 63 = max
    return v;
}
__device__ __forceinline__ float rlanef(float v, int l) {
    return __int_as_float(__builtin_amdgcn_readlane(__float_as_int(v), l));
}

// order-preserving float -> uint map (IEEE total order)
__device__ __forceinline__ unsigned xform(float f) {
    unsigned u = __float_as_uint(f);
    return (u & 0x80000000u) ? ~u : (u | 0x80000000u);
}

// (segmented) bitonic sort in LDS with all 1024 threads; segbound = pow2
__device__ __forceinline__ void bitonic_lds(unsigned* key, int tid, int segbound) {
    for (int k = 2; k <= segbound; k <<= 1) {
        for (int j = k >> 1; j > 0; j >>= 1) {
            __syncthreads();
            #pragma unroll
            for (int m = 0; m < 16; ++m) {
                int i = (m << 10) | tid;
                int l = i ^ j;
                if (l > i) {
                    unsigned a = key[i], c2 = key[l];
                    bool up = ((i & k) == 0);
                    if ((a > c2) == up) { key[i] = c2; key[l] = a; }
                }
            }
        }
    }
}

// -----------------------------------------------------------------------------
// TWO independent FPS batches per block sharing one barrier cadence.
// Waves 0-7 run batch 2*bid, waves 8-15 run batch 2*bid+1. Each batch uses the
// round-9 structure (best so far): rank-split grid -> 1024 tight cells of 16,
// per-cell exact skip test, whole-wave recompute with per-cell-half ballots,
// parity slots, 8-slot DPP phase C. Work per batch is unchanged; the win is
// TLP: one batch's recompute fills the other's barrier-skew/latency stalls
// (r9 counters: ~50% of cycles were stalls with all waves in one cadence).
// Exactness identical to rounds 7-12 (absmax=0): same fp32 ops/association,
// fl-monotone box bound + 0.9999 guard, first-original-index tie-breaks.
// -----------------------------------------------------------------------------
__global__ __launch_bounds__(NTHREADS, 1) void fps_kernel(
    const float* __restrict__ xyz, int* __restrict__ sorted_idx)
{
    __shared__ unsigned s_skey[NPTS];                   // 64KB, setup only
    __shared__ unsigned short s_ord[2][NPTS];           // 64KB, orig per slot
    __shared__ unsigned s_bitmap[2][NPTS / 32];         // 4KB
    __shared__ unsigned long long s_slot[2][2][NWSUB];  // [sub][parity][wave]
    __shared__ float s_ccf[2][2][NWSUB * 3];            // candidate coords
    __shared__ int s_wt[2][NWSUB];                      // tail scan totals

    const int tid  = threadIdx.x;
    const int lane = tid & 63;
    const int sub  = tid >> 9;          // 0 or 1: which batch
    const int tsub = tid & 511;         // thread id within sub-batch
    const int wsub = (tid >> 6) & 7;    // wave id within sub-batch

    s_bitmap[tid >> 9][tid & 511] = 0u;

    // ---- sort both halves (all 1024 threads cooperate per half) ----
    for (int h = 0; h < 2; ++h) {
        const float* xh = xyz + (size_t)(blockIdx.x * 2 + h) * NPTS * 3;
        #pragma unroll
        for (int k = 0; k < 16; ++k) {
            int i = (tid << 4) + k;
            s_skey[i] = (xform(xh[3 * i]) & 0xFFFFC000u) | (unsigned)i;
        }
        bitonic_lds(s_skey, tid, NPTS);          // by x
        __syncthreads();
        #pragma unroll
        for (int m = 0; m < 16; ++m) {
            int p2 = (m << 10) | tid;
            unsigned orig = s_skey[p2] & 0x3FFFu;
            s_skey[p2] = (xform(xh[3 * orig + 1]) & 0xFFFFC000u) | orig;
        }
        bitonic_lds(s_skey, tid, 2048);          // by y within 8 x-slabs
        __syncthreads();
        #pragma unroll
        for (int m = 0; m < 16; ++m) {
            int p2 = (m << 10) | tid;
            unsigned orig = s_skey[p2] & 0x3FFFu;
            s_skey[p2] = (xform(xh[3 * orig + 2]) & 0xFFFFC000u) | orig;
        }
        bitonic_lds(s_skey, tid, 256);           // by z within 64 columns
        __syncthreads();
        #pragma unroll
        for (int k = 0; k < 16; ++k) {
            int i = (tid << 4) + k;
            s_ord[h][i] = (unsigned short)(s_skey[i] & 0x3FFFu);
        }
        __syncthreads();
    }

    // ---- extraction: thread owns slots [32*tsub, 32*tsub+32) = 2 cells ----
    const int batch = blockIdx.x * 2 + sub;
    const float* xb = xyz + (size_t)batch * NPTS * 3;

    unsigned o[PPT];
    #pragma unroll
    for (int k = 0; k < PPT; ++k) o[k] = s_ord[sub][(tsub << 5) + k];
    // per-cell in-register odd-even sort ascending (exact tie-break basis)
    #pragma unroll
    for (int c = 0; c < 2; ++c) {
        #pragma unroll
        for (int r = 0; r < 16; ++r) {
            #pragma unroll
            for (int i = (r & 1); i + 1 < 16; i += 2) {
                unsigned lo = min(o[c * 16 + i], o[c * 16 + i + 1]);
                unsigned hi = max(o[c * 16 + i], o[c * 16 + i + 1]);
                o[c * 16 + i] = lo; o[c * 16 + i + 1] = hi;
            }
        }
    }
    #pragma unroll
    for (int k = 0; k < PPT; ++k)
        s_ord[sub][(tsub << 5) + k] = (unsigned short)o[k];   // own slots only

    // coords, per-cell tight boxes, pd init
    float px[PPT], py[PPT], pz[PPT], pd[PPT];
    float bxl[2], byl[2], bzl[2], bxh[2], byh[2], bzh[2];
    #pragma unroll
    for (int c = 0; c < 2; ++c) {
        bxl[c] = 1e30f; byl[c] = 1e30f; bzl[c] = 1e30f;
        bxh[c] = -1e30f; byh[c] = -1e30f; bzh[c] = -1e30f;
    }
    #pragma unroll
    for (int k = 0; k < PPT; ++k) {
        int g = (int)o[k];
        int c = k >> 4;
        px[k] = xb[3 * g]; py[k] = xb[3 * g + 1]; pz[k] = xb[3 * g + 2];
        pd[k] = 1e10f;
        bxl[c] = fminf(bxl[c], px[k]); bxh[c] = fmaxf(bxh[c], px[k]);
        byl[c] = fminf(byl[c], py[k]); byh[c] = fmaxf(byh[c], py[k]);
        bzl[c] = fminf(bzl[c], pz[k]); bzh[c] = fmaxf(bzh[c], pz[k]);
    }
    float tmaxA = 1e10f, tmaxB = 1e10f;
    // per-cell cached candidates (updated on each pass)
    unsigned oA = o[0], oB = o[16];
    float cxA = px[0], cyA = py[0], czA = pz[0];
    float cxB = px[16], cyB = py[16], czB = pz[16];
    // wave cached candidate (uniform)
    float mval = 1e10f, mcx = 0.f, mcy = 0.f, mcz = 0.f;
    unsigned morig = 0;

    float cx = xb[0], cy = xb[1], cz = xb[2];   // initial farthest = index 0
    if (tsub == 0) s_bitmap[sub][0] = 1u;
    __syncthreads();

    for (int s = 0; s < NSAMP - 1; ++s) {
        const int p = s & 1;

        // ---- per-cell exact skip tests ----
        float txA = fmaxf(fmaxf(__fsub_rn(bxl[0], cx), __fsub_rn(cx, bxh[0])), 0.f);
        float tyA = fmaxf(fmaxf(__fsub_rn(byl[0], cy), __fsub_rn(cy, byh[0])), 0.f);
        float tzA = fmaxf(fmaxf(__fsub_rn(bzl[0], cz), __fsub_rn(cz, bzh[0])), 0.f);
        float mdA = 0.9999f * __fadd_rn(__fadd_rn(__fmul_rn(txA, txA),
                                                  __fmul_rn(tyA, tyA)),
                                        __fmul_rn(tzA, tzA));
        float txB = fmaxf(fmaxf(__fsub_rn(bxl[1], cx), __fsub_rn(cx, bxh[1])), 0.f);
        float tyB = fmaxf(fmaxf(__fsub_rn(byl[1], cy), __fsub_rn(cy, byh[1])), 0.f);
        float tzB = fmaxf(fmaxf(__fsub_rn(bzl[1], cz), __fsub_rn(cz, bzh[1])), 0.f);
        float mdB = 0.9999f * __fadd_rn(__fadd_rn(__fmul_rn(txB, txB),
                                                  __fmul_rn(tyB, tyB)),
                                        __fmul_rn(tzB, tzB));
        unsigned long long balA = __ballot(mdA < tmaxA);
        unsigned long long balB = __ballot(mdB < tmaxB);

        if ((balA | balB) != 0ull) {          // wave-uniform recompute
            if (balA != 0ull) {               // pass over cell A halves
                float bv = -1.0f;
                #pragma unroll
                for (int k = 0; k < 16; ++k) {
                    float dx = __fsub_rn(px[k], cx);
                    float dy = __fsub_rn(py[k], cy);
                    float dz = __fsub_rn(pz[k], cz);
                    float d  = __fadd_rn(__fadd_rn(__fmul_rn(dx, dx),
                                                   __fmul_rn(dy, dy)),
                                         __fmul_rn(dz, dz));
                    float nd = fminf(pd[k], d);
                    pd[k] = nd;
                    bv = fmaxf(bv, nd);
                }
                tmaxA = bv;
                int bk = 0;
                #pragma unroll
                for (int k = 15; k >= 0; --k) if (pd[k] == bv) bk = k; // min k = min orig
                oA = (unsigned)s_ord[sub][(tsub << 5) + bk];
                float ax = px[0], ay = py[0], az = pz[0];
                #pragma unroll
                for (int k = 1; k < 16; ++k)
                    if (bk == k) { ax = px[k]; ay = py[k]; az = pz[k]; }
                cxA = ax; cyA = ay; czA = az;
            }
            if (balB != 0ull) {               // pass over cell B halves
                float bv = -1.0f;
                #pragma unroll
                for (int k = 16; k < 32; ++k) {
                    float dx = __fsub_rn(px[k], cx);
                    float dy = __fsub_rn(py[k], cy);
                    float dz = __fsub_rn(pz[k], cz);
                    float d  = __fadd_rn(__fadd_rn(__fmul_rn(dx, dx),
                                                   __fmul_rn(dy, dy)),
                                         __fmul_rn(dz, dz));
                    float nd = fminf(pd[k], d);
                    pd[k] = nd;
                    bv = fmaxf(bv, nd);
                }
                tmaxB = bv;
                int bk = 16;
                #pragma unroll
                for (int k = 31; k >= 16; --k) if (pd[k] == bv) bk = k;
                oB = (unsigned)s_ord[sub][(tsub << 5) + bk];
                float ax = px[16], ay = py[16], az = pz[16];
                #pragma unroll
                for (int k = 17; k < 32; ++k)
                    if (bk == k) { ax = px[k]; ay = py[k]; az = pz[k]; }
                cxB = ax; cyB = ay; czB = az;
            }
            // thread-best with exact cross-cell tie-break (min orig)
            bool pb = (tmaxB > tmaxA) || (tmaxB == tmaxA && oB < oA);
            float bv = pb ? tmaxB : tmaxA;
            unsigned bo = pb ? oB : oA;
            float ax = pb ? cxB : cxA, ay = pb ? cyB : cyA, az = pb ? czB : czA;

            // wave reduce: value max + ballot, exact min-orig on ties
            float wv = wave_max64(bv);
            int   mb = __builtin_amdgcn_readlane(__float_as_int(wv), 63);
            float mw = __int_as_float(mb);
            unsigned long long mk = __ballot(bv == mw);
            int sl;
            if (__popcll(mk) == 1) {
                sl = __ffsll(mk) - 1;
            } else {
                unsigned long long t = mk; unsigned best = 0xFFFFFFFFu; sl = 0;
                while (t) {
                    int l = __ffsll(t) - 1; t &= t - 1;
                    unsigned b2 = (unsigned)__builtin_amdgcn_readlane((int)bo, l);
                    if (b2 < best) { best = b2; sl = l; }
                }
            }
            mval  = mw;
            morig = (unsigned)__builtin_amdgcn_readlane((int)bo, sl);
            mcx = rlanef(ax, sl); mcy = rlanef(ay, sl); mcz = rlanef(az, sl);
        }

        // ---- publish (every wave, every iteration; parity avoids races) ----
        if (lane == 0) {
            s_slot[sub][p][wsub] =
                ((unsigned long long)(unsigned)__float_as_int(mval) << 32) | morig;
            s_ccf[sub][p][wsub * 3 + 0] = mcx;
            s_ccf[sub][p][wsub * 3 + 1] = mcy;
            s_ccf[sub][p][wsub * 3 + 2] = mcz;
        }

        __syncthreads();   // the ONLY barrier per iteration (shared by both batches)

        // ---- phase C: winner over this batch's 8 slots ----
        unsigned long long key = s_slot[sub][p][lane & 7];
        float cf = s_ccf[sub][p][lane < 24 ? lane : 0];
        float cv = __int_as_float((int)(key >> 32));
        int   ci = (int)(unsigned)key;
        float rv = cv;
        rv = fmaxf(rv, dpp_movf<0x111, 0xF>(rv));
        rv = fmaxf(rv, dpp_movf<0x112, 0xF>(rv));
        rv = fmaxf(rv, dpp_movf<0x114, 0xF>(rv));  // lane 7 of each 8-group = max
        int   gmb = __builtin_amdgcn_readlane(__float_as_int(rv), 7);
        float gm  = __int_as_float(gmb);
        unsigned long long m2 = __ballot(cv == gm);
        int w, g;
        if (__popcll(m2) == 8) {                   // unique winning wave (8 replicas)
            w = __ffsll(m2) - 1;
            g = __builtin_amdgcn_readlane(ci, w);
        } else {                                   // rare: min orig across waves
            unsigned long long t = m2 & 0xFFull;
            g = 0x7FFFFFFF; w = 0;
            while (t) {
                int l = __ffsll(t) - 1; t &= t - 1;
                int g2 = __builtin_amdgcn_readlane(ci, l);
                if (g2 < g) { g = g2; w = l; }
            }
        }
        cx = rlanef(cf, w * 3 + 0);
        cy = rlanef(cf, w * 3 + 1);
        cz = rlanef(cf, w * 3 + 2);

        if (tsub == 0) s_bitmap[sub][g >> 5] |= (1u << (g & 31));
    }
    __syncthreads();

    // ---- tail: per-batch bitmap -> ascending index list ----
    unsigned word = s_bitmap[sub][tsub];    // 512 words, one per thread
    int cnt = __popc(word);
    int inc = cnt;
    #pragma unroll
    for (int off = 1; off < 64; off <<= 1) {
        int n = __shfl_up(inc, off);
        if (lane >= off) inc += n;
    }
    if (lane == 63) s_wt[sub][wsub] = inc;
    __syncthreads();
    int base = inc - cnt;
    for (int w = 0; w < wsub; ++w) base += s_wt[sub][w];
    int* sb = sorted_idx + (size_t)batch * NSAMP;
    int pos = base;
    unsigned wmask = word;
    while (wmask) {
        int k = __ffs(wmask) - 1;
        wmask &= wmask - 1;
        sb[pos++] = tsub * 32 + k;
    }
}

// -----------------------------------------------------------------------------
// Gather kernel: one wave per sampled row.
//   out0 = new_xyz [B,S,3]; out1 = concat(xyz, points) [B,S,1,131]; out2 [B,S,128]
// -----------------------------------------------------------------------------
__global__ void gather_kernel(
    const float* __restrict__ xyz, const float* __restrict__ points,
    const float* __restrict__ pres, const int* __restrict__ sorted_idx,
    float* __restrict__ out0, float* __restrict__ out1, float* __restrict__ out2)
{
    int gw   = (int)((blockIdx.x * (unsigned)blockDim.x + threadIdx.x) >> 6);
    int lane = threadIdx.x & 63;
    if (gw >= BATCH * NSAMP) return;
    int b = gw >> 12;               // NSAMP == 4096
    int i = sorted_idx[gw];

    const float* xs = xyz    + ((size_t)b * NPTS + i) * 3;
    const float* ps = points + ((size_t)b * NPTS + i) * 128;
    const float* rs = pres   + ((size_t)b * NPTS + i) * 128;

    if (lane < 3) out0[(size_t)gw * 3 + lane] = xs[lane];

    float* o1 = out1 + (size_t)gw * 131;
    #pragma unroll
    for (int j = 0; j < 3; ++j) {
        int c = lane + 64 * j;
        if (c < 131) o1[c] = (c < 3) ? xs[c] : ps[c - 3];
    }

    const float2* r2 = (const float2*)rs;
    float2* o2 = (float2*)(out2 + (size_t)gw * 128);
    o2[lane] = r2[lane];
}

extern "C" void kernel_launch(void* const* d_in, const int* in_sizes, int n_in,
                              void* d_out, int out_size, void* d_ws, size_t ws_size,
                              hipStream_t stream)
{
    const float* xyz    = (const float*)d_in[0];
    const float* points = (const float*)d_in[1];
    const float* pres   = (const float*)d_in[2];

    float* out  = (float*)d_out;
    float* out0 = out;                                     // B*S*3
    float* out1 = out0 + (size_t)BATCH * NSAMP * 3;        // B*S*131
    float* out2 = out1 + (size_t)BATCH * NSAMP * 131;      // B*S*128

    int* sorted = (int*)d_ws;   // B*S ints = 256 KiB scratch

    fps_kernel<<<BATCH / 2, NTHREADS, 0, stream>>>(xyz, sorted);

    int total_threads = BATCH * NSAMP * 64;   // one wave per sampled row
    int threads = 256;
    int blocks  = total_threads / threads;
    gather_kernel<<<blocks, threads, 0, stream>>>(xyz, points, pres, sorted,
                                                  out0, out1, out2);
}

// Round 14
// 4889.855 us; speedup vs baseline: 5.8285x; 5.8285x over previous
//
#include <hip/hip_runtime.h>

// Problem constants (from setup_inputs: B=16, N=16384, D=128, S=N/4)
#define BATCH    16
#define NPTS     16384
#define NSAMP    4096
#define NTHREADS 1024
#define PPT      16
#define NWAVE    16

// DPP move helper (disabled lanes keep old value = own value)
template<int CTRL, int RM>
__device__ __forceinline__ float dpp_movf(float v) {
    return __int_as_float(__builtin_amdgcn_update_dpp(
        __float_as_int(v), __float_as_int(v), CTRL, RM, 0xF, false));
}

__device__ __forceinline__ float wave_max64(float v) {
    v = fmaxf(v, dpp_movf<0x111, 0xF>(v));   // row_shr:1
    v = fmaxf(v, dpp_movf<0x112, 0xF>(v));   // row_shr:2
    v = fmaxf(v, dpp_movf<0x114, 0xF>(v));   // row_shr:4
    v = fmaxf(v, dpp_movf<0x118, 0xF>(v));   // row_shr:8
    v = fmaxf(v, dpp_movf<0x142, 0xA>(v));   // row_bcast:15
    v = fmaxf(v, dpp_movf<0x143, 0xC>(v));   // row_bcast:31 -> lane 63 = max
    return v;
}

// order-preserving float -> uint map (IEEE total order)
__device__ __forceinline__ unsigned xform(float f) {
    unsigned u = __float_as_uint(f);
    return (u & 0x80000000u) ? ~u : (u | 0x80000000u);
}

// (segmented) bitonic sort of s_key in LDS; segbound = pow2 segment size
__device__ __forceinline__ void bitonic_lds(unsigned* s_key, int tid, int segbound) {
    for (int k = 2; k <= segbound; k <<= 1) {
        for (int j = k >> 1; j > 0; j >>= 1) {
            __syncthreads();
            #pragma unroll
            for (int m = 0; m < PPT; ++m) {
                int i = (m << 10) | tid;
                int l = i ^ j;
                if (l > i) {
                    unsigned a = s_key[i], c2 = s_key[l];
                    bool up = ((i & k) == 0);
                    if ((a > c2) == up) { s_key[i] = c2; s_key[l] = a; }
                }
            }
        }
    }
}

// -----------------------------------------------------------------------------
// FPS, rank-split grid (8 slabs x 8 cols x 16 z-cells of 16 pts), per-cell
// exact pruning -- round-9 structure (best measured: 4816us) with ONE change:
// wave regions remapped from (1 slab x 4 cols x 16z) [(8,2,1) arrangement,
// model/measured ~7.4 tripped waves/iter] to (2 slabs x 2 cols x 16z)
// [(4,4,1), model ~6.8]. Setup-time index permutation only; per-iteration
// code is byte-identical to round 9 (r10's regression came from its added
// per-iter pre-test and a WORSE (2,2,4) arrangement).
// Exact reference semantics: dist=min(dist,(dx2+dy2)+dz2) fp32 no-FMA,
// argmax first-original-index (all tie paths compare original indices).
// -----------------------------------------------------------------------------
__global__ __launch_bounds__(NTHREADS, 4) void fps_kernel(
    const float* __restrict__ xyz, int* __restrict__ sorted_idx)
{
    __shared__ unsigned s_key[NPTS];                 // 64 KiB
    __shared__ unsigned s_bitmap[NPTS / 32];         // 2 KiB
    __shared__ unsigned long long s_slot[2][NWAVE];  // parity {max_bits, orig}
    __shared__ float s_ccf[2][NWAVE * 3];            // parity candidate coords
    __shared__ int s_wt[NWAVE];                      // tail scan totals

    const int tid  = threadIdx.x;
    const int lane = tid & 63;
    const int wid  = tid >> 6;
    const int b    = blockIdx.x;

    if (tid < NPTS / 32) s_bitmap[tid] = 0u;

    const float* xb = xyz + (size_t)b * NPTS * 3;

    // ---- partition sort 1: by x (full 16384) ----
    #pragma unroll
    for (int k = 0; k < PPT; ++k) {
        int i = (tid << 4) + k;
        s_key[i] = (xform(xb[3 * i]) & 0xFFFFC000u) | (unsigned)i;
    }
    bitonic_lds(s_key, tid, NPTS);
    __syncthreads();

    // ---- sort 2: by y within 8 x-slabs of 2048 ----
    #pragma unroll
    for (int m = 0; m < PPT; ++m) {
        int p = (m << 10) | tid;
        unsigned orig = s_key[p] & 0x3FFFu;
        s_key[p] = (xform(xb[3 * orig + 1]) & 0xFFFFC000u) | orig;
    }
    bitonic_lds(s_key, tid, 2048);
    __syncthreads();

    // ---- sort 3: by z within 64 columns of 256 ----
    #pragma unroll
    for (int m = 0; m < PPT; ++m) {
        int p = (m << 10) | tid;
        unsigned orig = s_key[p] & 0x3FFFu;
        s_key[p] = (xform(xb[3 * orig + 2]) & 0xFFFFC000u) | orig;
    }
    bitonic_lds(s_key, tid, 256);
    __syncthreads();

    // ---- REGION REMAP (setup only): wave w owns slabs {2wx,2wx+1} x cols
    // {2wy,2wy+1} x all z, wx=w>>2, wy=w&3. Lane: slab-lsb(1)|col-lsb(1)|z(4).
    {
        int slab = ((wid >> 2) << 1) | (lane >> 5);        // 0..7
        int col  = ((wid & 3) << 1) | ((lane >> 4) & 1);   // 0..7
        int zc   = lane & 15;                              // 0..15
        int rsrc = (slab << 7) | (col << 4) | zc;          // source cell (rank order)
        unsigned o[PPT];
        #pragma unroll
        for (int k = 0; k < PPT; ++k) o[k] = s_key[(rsrc << 4) + k] & 0x3FFFu;
        __syncthreads();   // all cross-thread reads done before overwrite
        // in-register sort of the 16 origs ascending (odd-even network)
        #pragma unroll
        for (int r = 0; r < 16; ++r) {
            #pragma unroll
            for (int i = (r & 1); i + 1 < PPT; i += 2) {
                unsigned lo = min(o[i], o[i + 1]);
                unsigned hi = max(o[i], o[i + 1]);
                o[i] = lo; o[i + 1] = hi;
            }
        }
        #pragma unroll
        for (int k = 0; k < PPT; ++k) s_key[(tid << 4) + k] = o[k];
    }

    // ---- gather coords; tight cell bbox; init pd/tmax ----
    float px[PPT], py[PPT], pz[PPT], pd[PPT];
    float bxl = 1e30f, byl = 1e30f, bzl = 1e30f;
    float bxh = -1e30f, byh = -1e30f, bzh = -1e30f;
    #pragma unroll
    for (int k = 0; k < PPT; ++k) {
        int g = (int)s_key[(tid << 4) + k];
        px[k] = xb[3 * g]; py[k] = xb[3 * g + 1]; pz[k] = xb[3 * g + 2];
        pd[k] = 1e10f;
        bxl = fminf(bxl, px[k]); bxh = fmaxf(bxh, px[k]);
        byl = fminf(byl, py[k]); byh = fmaxf(byh, py[k]);
        bzl = fminf(bzl, pz[k]); bzh = fmaxf(bzh, pz[k]);
    }
    float tmax = 1e10f;

    // cached per-wave candidate (uniform); published while dirty
    float mval = 1e10f, mcx = 0.f, mcy = 0.f, mcz = 0.f;
    int   morig = 0, dirty = 0;

    float cx = xb[0], cy = xb[1], cz = xb[2];   // initial farthest = index 0
    if (tid == 0) s_bitmap[0] = 1u;
    __syncthreads();

    for (int s = 0; s < NSAMP - 1; ++s) {
        const int p = s & 1;

        // ---- per-thread exact skip test (tight cell box) ----
        float tx = fmaxf(fmaxf(__fsub_rn(bxl, cx), __fsub_rn(cx, bxh)), 0.f);
        float ty = fmaxf(fmaxf(__fsub_rn(byl, cy), __fsub_rn(cy, byh)), 0.f);
        float tz = fmaxf(fmaxf(__fsub_rn(bzl, cz), __fsub_rn(cz, bzh)), 0.f);
        float md2 = 0.9999f * __fadd_rn(__fadd_rn(__fmul_rn(tx, tx),
                                                  __fmul_rn(ty, ty)),
                                        __fmul_rn(tz, tz));
        if (__ballot(md2 < tmax) != 0ull) {   // recompute whole wave
            float bv = -1.0f;
            int   bk = 0;
            #pragma unroll
            for (int k = 0; k < PPT; ++k) {
                float dx = __fsub_rn(px[k], cx);
                float dy = __fsub_rn(py[k], cy);
                float dz = __fsub_rn(pz[k], cz);
                float d  = __fadd_rn(__fadd_rn(__fmul_rn(dx, dx),
                                               __fmul_rn(dy, dy)),
                                     __fmul_rn(dz, dz));
                float nd = fminf(pd[k], d);
                pd[k] = nd;
                if (nd > bv) { bv = nd; bk = k; }  // strict >: min orig (k sorted)
            }
            tmax = bv;
            int bo_mine = (int)s_key[(tid << 4) + bk];

            float wv = wave_max64(bv);
            int   mb = __builtin_amdgcn_readlane(__float_as_int(wv), 63);
            float mw = __int_as_float(mb);
            unsigned long long mk = __ballot(bv == mw);
            int sl, bo;
            if (__popcll(mk) == 1) {                   // unique max lane
                sl = __ffsll(mk) - 1;
                bo = __builtin_amdgcn_readlane(bo_mine, sl);
            } else {                                   // rare: min orig over ties
                unsigned long long t = mk;
                bo = 0x7FFFFFFF; sl = 0;
                while (t) {
                    int l = __ffsll(t) - 1; t &= t - 1;
                    int b2 = __builtin_amdgcn_readlane(bo_mine, l);
                    if (b2 < bo) { bo = b2; sl = l; }
                }
            }
            // candidate coords: every lane extracts its own, take lane sl's
            float ax = px[0], ay = py[0], az = pz[0];
            #pragma unroll
            for (int k = 1; k < PPT; ++k)
                if (bk == k) { ax = px[k]; ay = py[k]; az = pz[k]; }
            mcx = __int_as_float(__builtin_amdgcn_readlane(__float_as_int(ax), sl));
            mcy = __int_as_float(__builtin_amdgcn_readlane(__float_as_int(ay), sl));
            mcz = __int_as_float(__builtin_amdgcn_readlane(__float_as_int(az), sl));
            mval = mw; morig = bo; dirty = 2;
        }

        if (dirty > 0) {                   // publish cached candidate (both parities)
            if (lane == 0) {
                s_slot[p][wid] =
                    ((unsigned long long)(unsigned)__float_as_int(mval) << 32) |
                    (unsigned)morig;
                s_ccf[p][wid * 3 + 0] = mcx;
                s_ccf[p][wid * 3 + 1] = mcy;
                s_ccf[p][wid * 3 + 2] = mcz;
            }
            dirty -= 1;
        }

        __syncthreads();   // the ONLY barrier per iteration

        // ---- block winner over 16 wave slots; coords read in parallel ----
        unsigned long long key = s_slot[p][lane & 15];
        float cf = s_ccf[p][lane < 48 ? lane : 0];
        float cv = __int_as_float((int)(key >> 32));
        int   ci = (int)(unsigned)key;
        float rv = cv;
        rv = fmaxf(rv, dpp_movf<0x111, 0xF>(rv));
        rv = fmaxf(rv, dpp_movf<0x112, 0xF>(rv));
        rv = fmaxf(rv, dpp_movf<0x114, 0xF>(rv));
        rv = fmaxf(rv, dpp_movf<0x118, 0xF>(rv));  // lane 15 of row = max
        int   gmb = __builtin_amdgcn_readlane(__float_as_int(rv), 15);
        float gm  = __int_as_float(gmb);
        unsigned long long m2 = __ballot(cv == gm);
        int w, g;
        if (__popcll(m2) == 4) {                   // unique winning wave
            w = __ffsll(m2) - 1;
            g = __builtin_amdgcn_readlane(ci, w);
        } else {                                   // rare: min orig across waves
            unsigned long long t = m2 & 0xFFFFull;
            g = 0x7FFFFFFF; w = 0;
            while (t) {
                int l = __ffsll(t) - 1; t &= t - 1;
                int g2 = __builtin_amdgcn_readlane(ci, l);
                if (g2 < g) { g = g2; w = l; }
            }
        }
        cx = __int_as_float(__builtin_amdgcn_readlane(__float_as_int(cf), w * 3 + 0));
        cy = __int_as_float(__builtin_amdgcn_readlane(__float_as_int(cf), w * 3 + 1));
        cz = __int_as_float(__builtin_amdgcn_readlane(__float_as_int(cf), w * 3 + 2));

        if (tid == 0) s_bitmap[g >> 5] |= (1u << (g & 31));
    }
    __syncthreads();

    // ---- tail: bitmap -> ascending index list via block prefix scan ----
    const int nwords = NPTS / 32;   // 512
    unsigned word = (tid < nwords) ? s_bitmap[tid] : 0u;
    int cnt = __popc(word);
    int inc = cnt;
    #pragma unroll
    for (int off = 1; off < 64; off <<= 1) {
        int n = __shfl_up(inc, off);
        if (lane >= off) inc += n;
    }
    if (lane == 63) s_wt[wid] = inc;
    __syncthreads();
    int base = inc - cnt;
    for (int w = 0; w < wid; ++w) base += s_wt[w];
    int* sb = sorted_idx + (size_t)b * NSAMP;
    int pos = base;
    unsigned wmask = word;
    while (wmask) {
        int k = __ffs(wmask) - 1;
        wmask &= wmask - 1;
        sb[pos++] = tid * 32 + k;
    }
}

// -----------------------------------------------------------------------------
// Gather kernel: one wave per sampled row.
//   out0 = new_xyz [B,S,3]; out1 = concat(xyz, points) [B,S,1,131]; out2 [B,S,128]
// -----------------------------------------------------------------------------
__global__ void gather_kernel(
    const float* __restrict__ xyz, const float* __restrict__ points,
    const float* __restrict__ pres, const int* __restrict__ sorted_idx,
    float* __restrict__ out0, float* __restrict__ out1, float* __restrict__ out2)
{
    int gw   = (int)((blockIdx.x * (unsigned)blockDim.x + threadIdx.x) >> 6);
    int lane = threadIdx.x & 63;
    if (gw >= BATCH * NSAMP) return;
    int b = gw >> 12;               // NSAMP == 4096
    int i = sorted_idx[gw];

    const float* xs = xyz    + ((size_t)b * NPTS + i) * 3;
    const float* ps = points + ((size_t)b * NPTS + i) * 128;
    const float* rs = pres   + ((size_t)b * NPTS + i) * 128;

    if (lane < 3) out0[(size_t)gw * 3 + lane] = xs[lane];

    float* o1 = out1 + (size_t)gw * 131;
    #pragma unroll
    for (int j = 0; j < 3; ++j) {
        int c = lane + 64 * j;
        if (c < 131) o1[c] = (c < 3) ? xs[c] : ps[c - 3];
    }

    const float2* r2 = (const float2*)rs;
    float2* o2 = (float2*)(out2 + (size_t)gw * 128);
    o2[lane] = r2[lane];
}

extern "C" void kernel_launch(void* const* d_in, const int* in_sizes, int n_in,
                              void* d_out, int out_size, void* d_ws, size_t ws_size,
                              hipStream_t stream)
{
    const float* xyz    = (const float*)d_in[0];
    const float* points = (const float*)d_in[1];
    const float* pres   = (const float*)d_in[2];

    float* out  = (float*)d_out;
    float* out0 = out;                                     // B*S*3
    float* out1 = out0 + (size_t)BATCH * NSAMP * 3;        // B*S*131
    float* out2 = out1 + (size_t)BATCH * NSAMP * 131;      // B*S*128

    int* sorted = (int*)d_ws;   // B*S ints = 256 KiB scratch

    fps_kernel<<<BATCH, NTHREADS, 0, stream>>>(xyz, sorted);

    int total_threads = BATCH * NSAMP * 64;   // one wave per sampled row
    int threads = 256;
    int blocks  = total_threads / threads;
    gather_kernel<<<blocks, threads, 0, stream>>>(xyz, points, pres, sorted,
                                                  out0, out1, out2);
}

// Round 15
// 4818.139 us; speedup vs baseline: 5.9152x; 1.0149x over previous
//
#include <hip/hip_runtime.h>

// Problem constants (from setup_inputs: B=16, N=16384, D=128, S=N/4)
#define BATCH    16
#define NPTS     16384
#define NSAMP    4096
#define NTHREADS 1024
#define PPT      16
#define NWAVE    16

// DPP move helper (disabled lanes keep old value = own value)
template<int CTRL, int RM>
__device__ __forceinline__ float dpp_movf(float v) {
    return __int_as_float(__builtin_amdgcn_update_dpp(
        __float_as_int(v), __float_as_int(v), CTRL, RM, 0xF, false));
}

__device__ __forceinline__ float wave_max64(float v) {
    v = fmaxf(v, dpp_movf<0x111, 0xF>(v));   // row_shr:1
    v = fmaxf(v, dpp_movf<0x112, 0xF>(v));   // row_shr:2
    v = fmaxf(v, dpp_movf<0x114, 0xF>(v));   // row_shr:4
    v = fmaxf(v, dpp_movf<0x118, 0xF>(v));   // row_shr:8
    v = fmaxf(v, dpp_movf<0x142, 0xA>(v));   // row_bcast:15
    v = fmaxf(v, dpp_movf<0x143, 0xC>(v));   // row_bcast:31 -> lane 63 = max
    return v;
}

// order-preserving float -> uint map (IEEE total order)
__device__ __forceinline__ unsigned xform(float f) {
    unsigned u = __float_as_uint(f);
    return (u & 0x80000000u) ? ~u : (u | 0x80000000u);
}

// (segmented) bitonic sort of s_key in LDS; segbound = pow2 segment size
__device__ __forceinline__ void bitonic_lds(unsigned* s_key, int tid, int segbound) {
    for (int k = 2; k <= segbound; k <<= 1) {
        for (int j = k >> 1; j > 0; j >>= 1) {
            __syncthreads();
            #pragma unroll
            for (int m = 0; m < PPT; ++m) {
                int i = (m << 10) | tid;
                int l = i ^ j;
                if (l > i) {
                    unsigned a = s_key[i], c2 = s_key[l];
                    bool up = ((i & k) == 0);
                    if ((a > c2) == up) { s_key[i] = c2; s_key[l] = a; }
                }
            }
        }
    }
}

// -----------------------------------------------------------------------------
// FPS with per-thread exact pruning over a BALANCED RANK-SPLIT GRID.
// (Round-9 structure, best measured across 14 rounds: 4816us. Reverted
// verbatim after r10-r14 structural variants all regressed or were neutral.)
//  - 3 sorts build the partition: x -> 8 slabs(2048); y within slab -> 64
//    columns(256); z within column -> 1024 cells of 16 points. Every cell is
//    a tight disjoint box (rank splits nest -> no straddle).
//  - Thread t owns cell t: 16 points (orig-sorted in-register), tight bbox,
//    cached exact tmax = max of its pd. Skip lane when
//    0.9999*mindist(c,box)^2 >= tmax (fp-exact proof: fl-monotone per step,
//    same add association as reference, 0.9999 guard).
//  - Exact reference semantics: dist=min(dist,(dx2+dy2)+dz2) fp32 no-FMA,
//    argmax first-original-index (rare tie paths exact).
// -----------------------------------------------------------------------------
__global__ __launch_bounds__(NTHREADS, 4) void fps_kernel(
    const float* __restrict__ xyz, int* __restrict__ sorted_idx)
{
    __shared__ unsigned s_key[NPTS];                 // 64 KiB
    __shared__ unsigned s_bitmap[NPTS / 32];         // 2 KiB
    __shared__ unsigned long long s_slot[2][NWAVE];  // parity {max_bits, orig}
    __shared__ float s_ccf[2][NWAVE * 3];            // parity candidate coords
    __shared__ int s_wt[NWAVE];                      // tail scan totals

    const int tid  = threadIdx.x;
    const int lane = tid & 63;
    const int wid  = tid >> 6;
    const int b    = blockIdx.x;

    if (tid < NPTS / 32) s_bitmap[tid] = 0u;

    const float* xb = xyz + (size_t)b * NPTS * 3;

    // ---- partition sort 1: by x (full 16384) ----
    #pragma unroll
    for (int k = 0; k < PPT; ++k) {
        int i = (tid << 4) + k;
        s_key[i] = (xform(xb[3 * i]) & 0xFFFFC000u) | (unsigned)i;
    }
    bitonic_lds(s_key, tid, NPTS);
    __syncthreads();

    // ---- sort 2: by y within 8 x-slabs of 2048 ----
    #pragma unroll
    for (int m = 0; m < PPT; ++m) {
        int p = (m << 10) | tid;
        unsigned orig = s_key[p] & 0x3FFFu;
        s_key[p] = (xform(xb[3 * orig + 1]) & 0xFFFFC000u) | orig;
    }
    bitonic_lds(s_key, tid, 2048);
    __syncthreads();

    // ---- sort 3: by z within 64 columns of 256 ----
    #pragma unroll
    for (int m = 0; m < PPT; ++m) {
        int p = (m << 10) | tid;
        unsigned orig = s_key[p] & 0x3FFFu;
        s_key[p] = (xform(xb[3 * orig + 2]) & 0xFFFFC000u) | orig;
    }
    bitonic_lds(s_key, tid, 256);
    __syncthreads();

    // ---- per-thread cell: extract origs, in-register sort ascending ----
    unsigned o[PPT];
    #pragma unroll
    for (int k = 0; k < PPT; ++k) o[k] = s_key[(tid << 4) + k] & 0x3FFFu;
    #pragma unroll
    for (int r = 0; r < 16; ++r) {
        #pragma unroll
        for (int i = (r & 1); i + 1 < PPT; i += 2) {
            unsigned lo = min(o[i], o[i + 1]);
            unsigned hi = max(o[i], o[i + 1]);
            o[i] = lo; o[i + 1] = hi;
        }
    }
    #pragma unroll
    for (int k = 0; k < PPT; ++k) s_key[(tid << 4) + k] = o[k];

    // ---- gather coords; tight cell bbox; init pd/tmax ----
    float px[PPT], py[PPT], pz[PPT], pd[PPT];
    float bxl = 1e30f, byl = 1e30f, bzl = 1e30f;
    float bxh = -1e30f, byh = -1e30f, bzh = -1e30f;
    #pragma unroll
    for (int k = 0; k < PPT; ++k) {
        int g = (int)o[k];
        px[k] = xb[3 * g]; py[k] = xb[3 * g + 1]; pz[k] = xb[3 * g + 2];
        pd[k] = 1e10f;
        bxl = fminf(bxl, px[k]); bxh = fmaxf(bxh, px[k]);
        byl = fminf(byl, py[k]); byh = fmaxf(byh, py[k]);
        bzl = fminf(bzl, pz[k]); bzh = fmaxf(bzh, pz[k]);
    }
    float tmax = 1e10f;

    // cached per-wave candidate (uniform); published while dirty
    float mval = 1e10f, mcx = 0.f, mcy = 0.f, mcz = 0.f;
    int   morig = 0, dirty = 0;

    float cx = xb[0], cy = xb[1], cz = xb[2];   // initial farthest = index 0
    if (tid == 0) s_bitmap[0] = 1u;
    __syncthreads();

    for (int s = 0; s < NSAMP - 1; ++s) {
        const int p = s & 1;

        // ---- per-thread exact skip test (tight cell box) ----
        float tx = fmaxf(fmaxf(__fsub_rn(bxl, cx), __fsub_rn(cx, bxh)), 0.f);
        float ty = fmaxf(fmaxf(__fsub_rn(byl, cy), __fsub_rn(cy, byh)), 0.f);
        float tz = fmaxf(fmaxf(__fsub_rn(bzl, cz), __fsub_rn(cz, bzh)), 0.f);
        float md2 = 0.9999f * __fadd_rn(__fadd_rn(__fmul_rn(tx, tx),
                                                  __fmul_rn(ty, ty)),
                                        __fmul_rn(tz, tz));
        if (__ballot(md2 < tmax) != 0ull) {   // recompute whole wave
            float bv = -1.0f;
            int   bk = 0;
            #pragma unroll
            for (int k = 0; k < PPT; ++k) {
                float dx = __fsub_rn(px[k], cx);
                float dy = __fsub_rn(py[k], cy);
                float dz = __fsub_rn(pz[k], cz);
                float d  = __fadd_rn(__fadd_rn(__fmul_rn(dx, dx),
                                               __fmul_rn(dy, dy)),
                                     __fmul_rn(dz, dz));
                float nd = fminf(pd[k], d);
                pd[k] = nd;
                if (nd > bv) { bv = nd; bk = k; }  // strict >: min orig (k sorted)
            }
            tmax = bv;
            int bo_mine = (int)s_key[(tid << 4) + bk];

            float wv = wave_max64(bv);
            int   mb = __builtin_amdgcn_readlane(__float_as_int(wv), 63);
            float mw = __int_as_float(mb);
            unsigned long long mk = __ballot(bv == mw);
            int sl, bo;
            if (__popcll(mk) == 1) {                   // unique max lane
                sl = __ffsll(mk) - 1;
                bo = __builtin_amdgcn_readlane(bo_mine, sl);
            } else {                                   // rare: min orig over ties
                unsigned long long t = mk;
                bo = 0x7FFFFFFF; sl = 0;
                while (t) {
                    int l = __ffsll(t) - 1; t &= t - 1;
                    int b2 = __builtin_amdgcn_readlane(bo_mine, l);
                    if (b2 < bo) { bo = b2; sl = l; }
                }
            }
            // candidate coords: every lane extracts its own, take lane sl's
            float ax = px[0], ay = py[0], az = pz[0];
            #pragma unroll
            for (int k = 1; k < PPT; ++k)
                if (bk == k) { ax = px[k]; ay = py[k]; az = pz[k]; }
            mcx = __int_as_float(__builtin_amdgcn_readlane(__float_as_int(ax), sl));
            mcy = __int_as_float(__builtin_amdgcn_readlane(__float_as_int(ay), sl));
            mcz = __int_as_float(__builtin_amdgcn_readlane(__float_as_int(az), sl));
            mval = mw; morig = bo; dirty = 2;
        }

        if (dirty > 0) {                   // publish cached candidate (both parities)
            if (lane == 0) {
                s_slot[p][wid] =
                    ((unsigned long long)(unsigned)__float_as_int(mval) << 32) |
                    (unsigned)morig;
                s_ccf[p][wid * 3 + 0] = mcx;
                s_ccf[p][wid * 3 + 1] = mcy;
                s_ccf[p][wid * 3 + 2] = mcz;
            }
            dirty -= 1;
        }

        __syncthreads();   // the ONLY barrier per iteration

        // ---- block winner over 16 wave slots; coords read in parallel ----
        unsigned long long key = s_slot[p][lane & 15];
        float cf = s_ccf[p][lane < 48 ? lane : 0];
        float cv = __int_as_float((int)(key >> 32));
        int   ci = (int)(unsigned)key;
        float rv = cv;
        rv = fmaxf(rv, dpp_movf<0x111, 0xF>(rv));
        rv = fmaxf(rv, dpp_movf<0x112, 0xF>(rv));
        rv = fmaxf(rv, dpp_movf<0x114, 0xF>(rv));
        rv = fmaxf(rv, dpp_movf<0x118, 0xF>(rv));  // lane 15 of row = max
        int   gmb = __builtin_amdgcn_readlane(__float_as_int(rv), 15);
        float gm  = __int_as_float(gmb);
        unsigned long long m2 = __ballot(cv == gm);
        int w, g;
        if (__popcll(m2) == 4) {                   // unique winning wave
            w = __ffsll(m2) - 1;
            g = __builtin_amdgcn_readlane(ci, w);
        } else {                                   // rare: min orig across waves
            unsigned long long t = m2 & 0xFFFFull;
            g = 0x7FFFFFFF; w = 0;
            while (t) {
                int l = __ffsll(t) - 1; t &= t - 1;
                int g2 = __builtin_amdgcn_readlane(ci, l);
                if (g2 < g) { g = g2; w = l; }
            }
        }
        cx = __int_as_float(__builtin_amdgcn_readlane(__float_as_int(cf), w * 3 + 0));
        cy = __int_as_float(__builtin_amdgcn_readlane(__float_as_int(cf), w * 3 + 1));
        cz = __int_as_float(__builtin_amdgcn_readlane(__float_as_int(cf), w * 3 + 2));

        if (tid == 0) s_bitmap[g >> 5] |= (1u << (g & 31));
    }
    __syncthreads();

    // ---- tail: bitmap -> ascending index list via block prefix scan ----
    const int nwords = NPTS / 32;   // 512
    unsigned word = (tid < nwords) ? s_bitmap[tid] : 0u;
    int cnt = __popc(word);
    int inc = cnt;
    #pragma unroll
    for (int off = 1; off < 64; off <<= 1) {
        int n = __shfl_up(inc, off);
        if (lane >= off) inc += n;
    }
    if (lane == 63) s_wt[wid] = inc;
    __syncthreads();
    int base = inc - cnt;
    for (int w = 0; w < wid; ++w) base += s_wt[w];
    int* sb = sorted_idx + (size_t)b * NSAMP;
    int pos = base;
    unsigned wmask = word;
    while (wmask) {
        int k = __ffs(wmask) - 1;
        wmask &= wmask - 1;
        sb[pos++] = tid * 32 + k;
    }
}

// -----------------------------------------------------------------------------
// Gather kernel: one wave per sampled row.
//   out0 = new_xyz [B,S,3]; out1 = concat(xyz, points) [B,S,1,131]; out2 [B,S,128]
// -----------------------------------------------------------------------------
__global__ void gather_kernel(
    const float* __restrict__ xyz, const float* __restrict__ points,
    const float* __restrict__ pres, const int* __restrict__ sorted_idx,
    float* __restrict__ out0, float* __restrict__ out1, float* __restrict__ out2)
{
    int gw   = (int)((blockIdx.x * (unsigned)blockDim.x + threadIdx.x) >> 6);
    int lane = threadIdx.x & 63;
    if (gw >= BATCH * NSAMP) return;
    int b = gw >> 12;               // NSAMP == 4096
    int i = sorted_idx[gw];

    const float* xs = xyz    + ((size_t)b * NPTS + i) * 3;
    const float* ps = points + ((size_t)b * NPTS + i) * 128;
    const float* rs = pres   + ((size_t)b * NPTS + i) * 128;

    if (lane < 3) out0[(size_t)gw * 3 + lane] = xs[lane];

    float* o1 = out1 + (size_t)gw * 131;
    #pragma unroll
    for (int j = 0; j < 3; ++j) {
        int c = lane + 64 * j;
        if (c < 131) o1[c] = (c < 3) ? xs[c] : ps[c - 3];
    }

    const float2* r2 = (const float2*)rs;
    float2* o2 = (float2*)(out2 + (size_t)gw * 128);
    o2[lane] = r2[lane];
}

extern "C" void kernel_launch(void* const* d_in, const int* in_sizes, int n_in,
                              void* d_out, int out_size, void* d_ws, size_t ws_size,
                              hipStream_t stream)
{
    const float* xyz    = (const float*)d_in[0];
    const float* points = (const float*)d_in[1];
    const float* pres   = (const float*)d_in[2];

    float* out  = (float*)d_out;
    float* out0 = out;                                     // B*S*3
    float* out1 = out0 + (size_t)BATCH * NSAMP * 3;        // B*S*131
    float* out2 = out1 + (size_t)BATCH * NSAMP * 131;      // B*S*128

    int* sorted = (int*)d_ws;   // B*S ints = 256 KiB scratch

    fps_kernel<<<BATCH, NTHREADS, 0, stream>>>(xyz, sorted);

    int total_threads = BATCH * NSAMP * 64;   // one wave per sampled row
    int threads = 256;
    int blocks  = total_threads / threads;
    gather_kernel<<<blocks, threads, 0, stream>>>(xyz, points, pres, sorted,
                                                  out0, out1, out2);
}